// Round 3
// baseline (156.259 us; speedup 1.0000x reference)
//
#include <hip/hip_runtime.h>
#include <cstdint>
#include <cstddef>

// ---------------------------------------------------------------------------
// DeMash = complex GEMM: out[bts, m] = sum_l y[bts, l] * conj(C)[m, l]
//   out_r = Yr@Cr^T + Yi@Ci^T ; out_i = Yi@Cr^T - Yr@Ci^T
//
// R10: (a) prefetch double-buffer (T3-minimum template, m248v2): stage
// K-step t+1 BEFORE computing t, ONE barrier/iter; the vmcnt(0) inside
// __syncthreads then drains loads that had a full compute phase in
// flight (R9 residual: ~13 us of exposed load latency in the 2-barrier
// loop). BK 64->32 so 2 buffers fit the same 32 KB (3 blocks/CU kept).
// (b) 2 waves/block (128 thr), wave tile 32M x 64N': 12 ds_reads feed
// 32 MFMAs (0.375 reads/MFMA, was 0.5) -> ds_read 1.21 -> 0.91 GB.
// Port floor ~25 us, MFMA floor ~16 us. acc 128 VGPR (4 products x 2x4).
//   A2 [2048][3072] fp16 : [Yr(1536, zero-padded from 1512) | Yi(1536)]
//   W2 [1536][3072] fp16 : [Cr(1536) | Ci(1536)]
// XOR chunk swizzle at 8 chunks/row: stage g = slot^(row&7); read
// chunk q at slot q^(fr&7); worst 2-way bank aliasing (free, m136).
// prep_all unchanged (R9).
// ---------------------------------------------------------------------------

typedef _Float16 half_t;
typedef half_t half8 __attribute__((ext_vector_type(8)));
typedef half_t half4 __attribute__((ext_vector_type(4)));
typedef half_t half2_t __attribute__((ext_vector_type(2)));
typedef float floatx4 __attribute__((ext_vector_type(4)));
typedef float floatv4 __attribute__((ext_vector_type(4)));

#define M_DIM 2048
#define K_DIM 3072            // [Yr 1536 | Yi 1536]
#define L_PAD 1536            // 1512 padded to 48*32
#define N2_DIM 1536           // W2 rows (n' padded)
#define LDIM 1512
#define NSC 108
#define SYMS 14
#define FFT 128
#define ROWLEN (SYMS * FFT)   // 1792

#define BM 64
#define BN 64                 // N' tile (complex columns)
#define BK 32                 // l-step per iteration (per buffer)
#define NITER (L_PAD / BK)    // 48

// prep grid partition (blocks of 256 threads)
#define PA2_BLOCKS 6048   // A: 2048 rows x 14 syms x 54 j-pairs / 256
#define PW2_BLOCKS 4608   // W2: 1536 rows x 768 k-quads / 256
#define PAP_BLOCKS 48     // A pad zero: 2048 x 48 halves / 8 / 256
#define PG_BLOCKS 4480    // guard zero: 2*2048*14*20 / 256
#define PREP_BLOCKS (PA2_BLOCKS + PW2_BLOCKS + PAP_BLOCKS + PG_BLOCKS)

typedef __attribute__((address_space(3))) uint32_t lds_u32_t;
typedef const __attribute__((address_space(1))) uint32_t glob_u32_t;

__device__ __forceinline__ void gl2lds16(const void* g, void* l) {
    __builtin_amdgcn_global_load_lds((glob_u32_t*)g, (lds_u32_t*)l, 16, 0, 0);
}

// ---------------------------------------------------------------------------
// prep_all (one dispatch, 4 regions, wave-uniform region branch):
//  [0, PA2): A-build. Yr at col sym*108+2jp, Yi at +1536.
//  [PA2, +PW2): W2-build. row n'<1536: cols [0,1536)=Cr[n'], [1536,3072)=Ci.
//            zero when n'>=1512 or l>=1512. float4 load, half4 store.
//  then A pad zeros (cols 1512..1535 and 3048..3071), then guard zeros.
// ---------------------------------------------------------------------------
__global__ __launch_bounds__(256) void prep_all(
    const float* __restrict__ xr, const float* __restrict__ xi,
    const float* __restrict__ Cr, const float* __restrict__ Ci,
    const int* __restrict__ sc,
    half_t* __restrict__ A, half_t* __restrict__ W, float* __restrict__ out)
{
    const int b = blockIdx.x;
    const int t = threadIdx.x;

    if (b < PA2_BLOCKS) {
        int idx = b * 256 + t;          // [0, 2048*14*54)
        int jp = idx % 54;
        int rest = idx / 54;
        int sym = rest % 14;
        int row = rest / 14;
        int s0 = sc[2 * jp];
        int s1 = sc[2 * jp + 1];
        const float* xrp = xr + (size_t)row * ROWLEN + sym * FFT;
        const float* xip = xi + (size_t)row * ROWLEN + sym * FFT;
        half2_t hr = { (half_t)xrp[s0], (half_t)xrp[s1] };
        half2_t hi = { (half_t)xip[s0], (half_t)xip[s1] };
        size_t dst = (size_t)row * K_DIM + sym * NSC + 2 * jp;
        *(half2_t*)(A + dst) = hr;
        *(half2_t*)(A + dst + L_PAD) = hi;
    } else if (b < PA2_BLOCKS + PW2_BLOCKS) {
        int idx = (b - PA2_BLOCKS) * 256 + t;   // [0, 1536*768)
        int kq = idx % 768;
        int n = idx / 768;
        int k0 = kq * 4;
        floatv4 f = {0.0f, 0.0f, 0.0f, 0.0f};
        if (n < LDIM) {
            if (k0 < L_PAD) {
                if (k0 < LDIM)
                    f = *(const floatv4*)(Cr + (size_t)n * LDIM + k0);
            } else {
                int l = k0 - L_PAD;
                if (l < LDIM)
                    f = *(const floatv4*)(Ci + (size_t)n * LDIM + l);
            }
        }
        half4 h = { (half_t)f.x, (half_t)f.y, (half_t)f.z, (half_t)f.w };
        *(half4*)(W + (size_t)n * K_DIM + k0) = h;
    } else if (b < PA2_BLOCKS + PW2_BLOCKS + PAP_BLOCKS) {
        int idx = (b - PA2_BLOCKS - PW2_BLOCKS) * 256 + t;  // [0, 12288)
        int c = idx % 6;
        int row = idx / 6;
        int col = (c < 3) ? (LDIM + c * 8) : (L_PAD + LDIM + (c - 3) * 8);
        half8 z = {};
        *(half8*)(A + (size_t)row * K_DIM + col) = z;
    } else {
        // zero guard columns [0,10) U [118,128) for all 4096 rows x 14 syms
        int idx = (b - PA2_BLOCKS - PW2_BLOCKS - PAP_BLOCKS) * 256 + t;
        int c20 = idx % 20;
        int rest = idx / 20;
        int sym = rest % 14;
        int rowri = rest / 14;                 // [0, 4096) covers both ri
        int col = (c20 < 10) ? c20 : (NSC + c20);
        out[(size_t)rowri * ROWLEN + sym * FFT + col] = 0.0f;
    }
}

// ---------------------------------------------------------------------------
// gemm_scatter: complex 64x64 tile, 2 waves (128 thr), each 32M x 64N'
// (2x4 frags x 4 products RR,II,IR,RI). Prefetch double-buffer, BK=32:
//   prologue: stage(buf0, kb=0); barrier
//   iter kb:  stage(buf^1, kb+1); ds_read+MFMA on buf; barrier
// One barrier/iter; its vmcnt(0) drains loads issued a full compute
// phase earlier. LDS 4 x 8 KB = 32 KB -> grid 768 = 3 blocks/CU.
// Per-buffer row = 64 halves (32 Yr/Cr + 32 Yi/Ci) = 8 chunks of 16B;
// stage chunk g at slot g^(row&7), read chunk q at slot q^(fr&7).
// ---------------------------------------------------------------------------
__global__ __launch_bounds__(128, 2) void gemm_scatter(
    const half_t* __restrict__ A,   // [M_DIM][K_DIM]  [Yr|Yi]
    const half_t* __restrict__ W,   // [N2_DIM][K_DIM] [Cr|Ci]
    const int* __restrict__ sc,
    float* __restrict__ out)        // [2][2048][14][128]; guards pre-zeroed
{
    __shared__ __align__(16) half_t As[2][BM * 2 * BK];   // 2 x 8 KB
    __shared__ __align__(16) half_t Ws[2][BN * 2 * BK];   // 2 x 8 KB

    const int t = threadIdx.x;        // 0..127
    const int bn = blockIdx.x;
    const int bm = blockIdx.y;
    const int lane = t & 63;
    const int w = t >> 6;             // 0..1
    const int wm = w * 32;            // wave M offset in tile

    floatx4 aRR[2][4] = {}, aII[2][4] = {}, aIR[2][4] = {}, aRI[2][4] = {};

    // staging: per buffer 512 chunks (16B); chunk c: row = c>>3,
    // slot = c&7, global chunk g = slot ^ (row&7); g<4 -> Yr/Cr col g*8,
    // g>=4 -> Yi/Ci col 1536+(g-4)*8. LDS dest = base + c*16.
    const half_t* gA[4];
    const half_t* gW[4];
    int lOff[4];
#pragma unroll
    for (int r = 0; r < 4; ++r) {
        int c = r * 128 + t;
        int row = c >> 3, slot = c & 7;
        int g = slot ^ (row & 7);
        int gcol = (g < 4) ? g * 8 : (L_PAD + (g - 4) * 8);
        gA[r] = A + (size_t)(bm * BM + row) * K_DIM + gcol;
        gW[r] = W + (size_t)(bn * BN + row) * K_DIM + gcol;
        lOff[r] = c * 8;
    }

    const int fr = lane & 15;         // fragment row (M or N' within 16)
    const int cr = lane >> 4;         // k-quad index within the 32-k step
    const int sR = ((cr ^ (fr & 7))) * 8;            // Yr/Cr chunk slot
    const int sI = (((4 + cr) ^ (fr & 7))) * 8;      // Yi/Ci chunk slot

    // prologue: stage kb=0 into buf 0
#pragma unroll
    for (int r = 0; r < 4; ++r) {
        gl2lds16(gA[r], &As[0][lOff[r]]);
        gl2lds16(gW[r], &Ws[0][lOff[r]]);
        gA[r] += BK; gW[r] += BK;
    }
    __syncthreads();

    for (int kb = 0; kb < NITER; ++kb) {
        const int nb = kb & 1;
        if (kb < NITER - 1) {
#pragma unroll
            for (int r = 0; r < 4; ++r) {
                gl2lds16(gA[r], &As[nb ^ 1][lOff[r]]);
                gl2lds16(gW[r], &Ws[nb ^ 1][lOff[r]]);
                gA[r] += BK; gW[r] += BK;
            }
        }

        half8 yr[2], yi[2], cRf[4], cIf[4];
#pragma unroll
        for (int i = 0; i < 2; ++i) {
            const half_t* rb = &As[nb][(wm + i * 16 + fr) * (2 * BK)];
            yr[i] = *(const half8*)(rb + sR);
            yi[i] = *(const half8*)(rb + sI);
        }
#pragma unroll
        for (int j = 0; j < 4; ++j) {
            const half_t* rb = &Ws[nb][(j * 16 + fr) * (2 * BK)];
            cRf[j] = *(const half8*)(rb + sR);
            cIf[j] = *(const half8*)(rb + sI);
        }
#pragma unroll
        for (int i = 0; i < 2; ++i)
#pragma unroll
            for (int j = 0; j < 4; ++j) {
                aRR[i][j] = __builtin_amdgcn_mfma_f32_16x16x32_f16(
                    yr[i], cRf[j], aRR[i][j], 0, 0, 0);
                aII[i][j] = __builtin_amdgcn_mfma_f32_16x16x32_f16(
                    yi[i], cIf[j], aII[i][j], 0, 0, 0);
                aIR[i][j] = __builtin_amdgcn_mfma_f32_16x16x32_f16(
                    yi[i], cRf[j], aIR[i][j], 0, 0, 0);
                aRI[i][j] = __builtin_amdgcn_mfma_f32_16x16x32_f16(
                    yr[i], cIf[j], aRI[i][j], 0, 0, 0);
            }
        __syncthreads();
    }

    // epilogue: C/D layout col = lane&15 (N'), row = (lane>>4)*4 + reg (M)
    const int rq = lane >> 4;
#pragma unroll
    for (int j = 0; j < 4; ++j) {
        int n = bn * BN + j * 16 + fr;
        if (n >= LDIM) continue;               // N'-pad: discard
        int sym = n / NSC;
        int jj = n - sym * NSC;
        size_t colR = (size_t)sym * FFT + sc[jj];
        size_t colI = (size_t)M_DIM * ROWLEN + colR;
#pragma unroll
        for (int i = 0; i < 2; ++i) {
            int m0 = bm * BM + wm + i * 16 + rq * 4;
#pragma unroll
            for (int r = 0; r < 4; ++r) {
                float vr = aRR[i][j][r] + aII[i][j][r];
                float vi = aIR[i][j][r] - aRI[i][j][r];
                out[colR + (size_t)(m0 + r) * ROWLEN] = vr;
                out[colI + (size_t)(m0 + r) * ROWLEN] = vi;
            }
        }
    }
}

// ---------------------------------------------------------------------------
extern "C" void kernel_launch(void* const* d_in, const int* in_sizes, int n_in,
                              void* d_out, int out_size, void* d_ws, size_t ws_size,
                              hipStream_t stream) {
    const float* xr = (const float*)d_in[0];
    const float* xi = (const float*)d_in[1];
    const float* Cr = (const float*)d_in[2];
    const float* Ci = (const float*)d_in[3];
    const int* sc   = (const int*)d_in[4];
    float* out = (float*)d_out;

    half_t* Ah = (half_t*)d_ws;                                      // 12.58 MB
    half_t* Wh = (half_t*)((char*)d_ws + (size_t)M_DIM * K_DIM * 2); // 9.44 MB

    prep_all<<<PREP_BLOCKS, 256, 0, stream>>>(
        xr, xi, Cr, Ci, sc, Ah, Wh, out);

    dim3 grid(N2_DIM / BN, M_DIM / BM);   // (24, 32) = 768 blocks
    gemm_scatter<<<grid, 128, 0, stream>>>(Ah, Wh, sc, out);
}

// Round 4
// 153.037 us; speedup vs baseline: 1.0211x; 1.0211x over previous
//
#include <hip/hip_runtime.h>
#include <cstdint>
#include <cstddef>

// ---------------------------------------------------------------------------
// DeMash = complex GEMM: out[bts, m] = sum_l y[bts, l] * conj(C)[m, l]
//   out_r = Yr@Cr^T + Yi@Ci^T ; out_i = Yi@Cr^T - Yr@Ci^T
//
// R11: R10 post-mortem -- the dbuf schedule was right but 128-thr blocks
// dropped occupancy 12->6 waves/CU and regressed. R11 = R9's proven
// geometry (256 thr, 4 waves 2x2, 64x64 tile, 768 blocks = 3/CU,
// 12 waves/CU, 32 KB LDS) with ONLY the pipeline changed:
//   BK 64->32, two buffers (2x8KB A + 2x8KB W = same 32 KB),
//   prefetch step t+1 issued BEFORE compute of step t, ONE barrier/iter.
// The vmcnt(0) inside __syncthreads now drains loads that had a full
// compute phase in flight (R9 exposed them cold). Barrier count same
// (48); each drain overlapped.
//   A2 [2048][3072] fp16 : [Yr(1536, zero-padded from 1512) | Yi(1536)]
//   W2 [1536][3072] fp16 : [Cr(1536) | Ci(1536)]
// Per-buffer row = 64 halves (32 Yr/Cr + 32 Yi/Ci) = 8 chunks of 16B;
// stage chunk g at slot g^(row&7), read chunk q at slot q^(fr&7);
// worst 2-way bank aliasing (free, m136). prep_all unchanged (R9).
// ---------------------------------------------------------------------------

typedef _Float16 half_t;
typedef half_t half8 __attribute__((ext_vector_type(8)));
typedef half_t half4 __attribute__((ext_vector_type(4)));
typedef half_t half2_t __attribute__((ext_vector_type(2)));
typedef float floatx4 __attribute__((ext_vector_type(4)));
typedef float floatv4 __attribute__((ext_vector_type(4)));

#define M_DIM 2048
#define K_DIM 3072            // [Yr 1536 | Yi 1536]
#define L_PAD 1536            // 1512 padded to 48*32
#define N2_DIM 1536           // W2 rows (n' padded)
#define LDIM 1512
#define NSC 108
#define SYMS 14
#define FFT 128
#define ROWLEN (SYMS * FFT)   // 1792

#define BM 64
#define BN 64                 // N' tile (complex columns)
#define BK 32                 // l-step per iteration (per buffer)
#define NITER (L_PAD / BK)    // 48

// prep grid partition (blocks of 256 threads)
#define PA2_BLOCKS 6048   // A: 2048 rows x 14 syms x 54 j-pairs / 256
#define PW2_BLOCKS 4608   // W2: 1536 rows x 768 k-quads / 256
#define PAP_BLOCKS 48     // A pad zero: 2048 x 48 halves / 8 / 256
#define PG_BLOCKS 4480    // guard zero: 2*2048*14*20 / 256
#define PREP_BLOCKS (PA2_BLOCKS + PW2_BLOCKS + PAP_BLOCKS + PG_BLOCKS)

typedef __attribute__((address_space(3))) uint32_t lds_u32_t;
typedef const __attribute__((address_space(1))) uint32_t glob_u32_t;

__device__ __forceinline__ void gl2lds16(const void* g, void* l) {
    __builtin_amdgcn_global_load_lds((glob_u32_t*)g, (lds_u32_t*)l, 16, 0, 0);
}

// ---------------------------------------------------------------------------
// prep_all (one dispatch, 4 regions, wave-uniform region branch):
//  [0, PA2): A-build. Yr at col sym*108+2jp, Yi at +1536.
//  [PA2, +PW2): W2-build. row n'<1536: cols [0,1536)=Cr[n'], [1536,3072)=Ci.
//            zero when n'>=1512 or l>=1512. float4 load, half4 store.
//  then A pad zeros (cols 1512..1535 and 3048..3071), then guard zeros.
// ---------------------------------------------------------------------------
__global__ __launch_bounds__(256) void prep_all(
    const float* __restrict__ xr, const float* __restrict__ xi,
    const float* __restrict__ Cr, const float* __restrict__ Ci,
    const int* __restrict__ sc,
    half_t* __restrict__ A, half_t* __restrict__ W, float* __restrict__ out)
{
    const int b = blockIdx.x;
    const int t = threadIdx.x;

    if (b < PA2_BLOCKS) {
        int idx = b * 256 + t;          // [0, 2048*14*54)
        int jp = idx % 54;
        int rest = idx / 54;
        int sym = rest % 14;
        int row = rest / 14;
        int s0 = sc[2 * jp];
        int s1 = sc[2 * jp + 1];
        const float* xrp = xr + (size_t)row * ROWLEN + sym * FFT;
        const float* xip = xi + (size_t)row * ROWLEN + sym * FFT;
        half2_t hr = { (half_t)xrp[s0], (half_t)xrp[s1] };
        half2_t hi = { (half_t)xip[s0], (half_t)xip[s1] };
        size_t dst = (size_t)row * K_DIM + sym * NSC + 2 * jp;
        *(half2_t*)(A + dst) = hr;
        *(half2_t*)(A + dst + L_PAD) = hi;
    } else if (b < PA2_BLOCKS + PW2_BLOCKS) {
        int idx = (b - PA2_BLOCKS) * 256 + t;   // [0, 1536*768)
        int kq = idx % 768;
        int n = idx / 768;
        int k0 = kq * 4;
        floatv4 f = {0.0f, 0.0f, 0.0f, 0.0f};
        if (n < LDIM) {
            if (k0 < L_PAD) {
                if (k0 < LDIM)
                    f = *(const floatv4*)(Cr + (size_t)n * LDIM + k0);
            } else {
                int l = k0 - L_PAD;
                if (l < LDIM)
                    f = *(const floatv4*)(Ci + (size_t)n * LDIM + l);
            }
        }
        half4 h = { (half_t)f.x, (half_t)f.y, (half_t)f.z, (half_t)f.w };
        *(half4*)(W + (size_t)n * K_DIM + k0) = h;
    } else if (b < PA2_BLOCKS + PW2_BLOCKS + PAP_BLOCKS) {
        int idx = (b - PA2_BLOCKS - PW2_BLOCKS) * 256 + t;  // [0, 12288)
        int c = idx % 6;
        int row = idx / 6;
        int col = (c < 3) ? (LDIM + c * 8) : (L_PAD + LDIM + (c - 3) * 8);
        half8 z = {};
        *(half8*)(A + (size_t)row * K_DIM + col) = z;
    } else {
        // zero guard columns [0,10) U [118,128) for all 4096 rows x 14 syms
        int idx = (b - PA2_BLOCKS - PW2_BLOCKS - PAP_BLOCKS) * 256 + t;
        int c20 = idx % 20;
        int rest = idx / 20;
        int sym = rest % 14;
        int rowri = rest / 14;                 // [0, 4096) covers both ri
        int col = (c20 < 10) ? c20 : (NSC + c20);
        out[(size_t)rowri * ROWLEN + sym * FFT + col] = 0.0f;
    }
}

// ---------------------------------------------------------------------------
// gemm_scatter: complex 64x64 tile, 4 waves (2x2), each 32M x 32N'
// (2x2 frags x 4 products RR,II,IR,RI). Prefetch double-buffer, BK=32:
//   prologue: stage(buf0, kb=0); barrier
//   iter kb:  stage(buf^1, kb+1); ds_read+MFMA on buf; barrier
// One barrier/iter; its vmcnt(0) drains loads issued a full compute
// phase earlier. LDS 4 x 8 KB = 32 KB -> grid 768 = 3 blocks/CU,
// 12 waves/CU (R9 occupancy restored).
// Per-buffer row = 64 halves = 8 chunks of 16B; stage chunk g at slot
// g^(row&7), read chunk q at slot q^(fr&7).
// ---------------------------------------------------------------------------
__global__ __launch_bounds__(256, 3) void gemm_scatter(
    const half_t* __restrict__ A,   // [M_DIM][K_DIM]  [Yr|Yi]
    const half_t* __restrict__ W,   // [N2_DIM][K_DIM] [Cr|Ci]
    const int* __restrict__ sc,
    float* __restrict__ out)        // [2][2048][14][128]; guards pre-zeroed
{
    __shared__ __align__(16) half_t As[2][BM * 2 * BK];   // 2 x 8 KB
    __shared__ __align__(16) half_t Ws[2][BN * 2 * BK];   // 2 x 8 KB

    const int t = threadIdx.x;        // 0..255
    const int bn = blockIdx.x;
    const int bm = blockIdx.y;
    const int lane = t & 63;
    const int w = t >> 6;             // 0..3
    const int wm = (w >> 1) * 32;     // wave M offset in tile
    const int wn = (w & 1) * 32;      // wave N' offset in tile

    floatx4 aRR[2][2] = {}, aII[2][2] = {}, aIR[2][2] = {}, aRI[2][2] = {};

    // staging: per buffer 512 chunks (16B); chunk c: row = c>>3,
    // slot = c&7, global chunk g = slot ^ (row&7); g<4 -> Yr/Cr col g*8,
    // g>=4 -> Yi/Ci col 1536+(g-4)*8. LDS dest = base + c*16.
    const half_t* gA[2];
    const half_t* gW[2];
    int lOff[2];
#pragma unroll
    for (int r = 0; r < 2; ++r) {
        int c = r * 256 + t;
        int row = c >> 3, slot = c & 7;
        int g = slot ^ (row & 7);
        int gcol = (g < 4) ? g * 8 : (L_PAD + (g - 4) * 8);
        gA[r] = A + (size_t)(bm * BM + row) * K_DIM + gcol;
        gW[r] = W + (size_t)(bn * BN + row) * K_DIM + gcol;
        lOff[r] = c * 8;
    }

    const int fr = lane & 15;         // fragment row (M or N' within 16)
    const int cr = lane >> 4;         // k-quad index within the 32-k step
    const int sR = (cr ^ (fr & 7)) * 8;            // Yr/Cr chunk slot
    const int sI = ((4 + cr) ^ (fr & 7)) * 8;      // Yi/Ci chunk slot

    // prologue: stage kb=0 into buf 0
#pragma unroll
    for (int r = 0; r < 2; ++r) {
        gl2lds16(gA[r], &As[0][lOff[r]]);
        gl2lds16(gW[r], &Ws[0][lOff[r]]);
        gA[r] += BK; gW[r] += BK;
    }
    __syncthreads();

    for (int kb = 0; kb < NITER; ++kb) {
        const int nb = kb & 1;
        if (kb < NITER - 1) {
#pragma unroll
            for (int r = 0; r < 2; ++r) {
                gl2lds16(gA[r], &As[nb ^ 1][lOff[r]]);
                gl2lds16(gW[r], &Ws[nb ^ 1][lOff[r]]);
                gA[r] += BK; gW[r] += BK;
            }
        }

        half8 yr[2], yi[2], cRf[2], cIf[2];
#pragma unroll
        for (int i = 0; i < 2; ++i) {
            const half_t* rb = &As[nb][(wm + i * 16 + fr) * (2 * BK)];
            yr[i] = *(const half8*)(rb + sR);
            yi[i] = *(const half8*)(rb + sI);
        }
#pragma unroll
        for (int j = 0; j < 2; ++j) {
            const half_t* rb = &Ws[nb][(wn + j * 16 + fr) * (2 * BK)];
            cRf[j] = *(const half8*)(rb + sR);
            cIf[j] = *(const half8*)(rb + sI);
        }
#pragma unroll
        for (int i = 0; i < 2; ++i)
#pragma unroll
            for (int j = 0; j < 2; ++j) {
                aRR[i][j] = __builtin_amdgcn_mfma_f32_16x16x32_f16(
                    yr[i], cRf[j], aRR[i][j], 0, 0, 0);
                aII[i][j] = __builtin_amdgcn_mfma_f32_16x16x32_f16(
                    yi[i], cIf[j], aII[i][j], 0, 0, 0);
                aIR[i][j] = __builtin_amdgcn_mfma_f32_16x16x32_f16(
                    yi[i], cRf[j], aIR[i][j], 0, 0, 0);
                aRI[i][j] = __builtin_amdgcn_mfma_f32_16x16x32_f16(
                    yr[i], cIf[j], aRI[i][j], 0, 0, 0);
            }
        __syncthreads();
    }

    // epilogue: C/D layout col = lane&15 (N'), row = (lane>>4)*4 + reg (M)
    const int rq = lane >> 4;
#pragma unroll
    for (int j = 0; j < 2; ++j) {
        int n = bn * BN + wn + j * 16 + fr;
        if (n >= LDIM) continue;               // N'-pad: discard
        int sym = n / NSC;
        int jj = n - sym * NSC;
        size_t colR = (size_t)sym * FFT + sc[jj];
        size_t colI = (size_t)M_DIM * ROWLEN + colR;
#pragma unroll
        for (int i = 0; i < 2; ++i) {
            int m0 = bm * BM + wm + i * 16 + rq * 4;
#pragma unroll
            for (int r = 0; r < 4; ++r) {
                float vr = aRR[i][j][r] + aII[i][j][r];
                float vi = aIR[i][j][r] - aRI[i][j][r];
                out[colR + (size_t)(m0 + r) * ROWLEN] = vr;
                out[colI + (size_t)(m0 + r) * ROWLEN] = vi;
            }
        }
    }
}

// ---------------------------------------------------------------------------
extern "C" void kernel_launch(void* const* d_in, const int* in_sizes, int n_in,
                              void* d_out, int out_size, void* d_ws, size_t ws_size,
                              hipStream_t stream) {
    const float* xr = (const float*)d_in[0];
    const float* xi = (const float*)d_in[1];
    const float* Cr = (const float*)d_in[2];
    const float* Ci = (const float*)d_in[3];
    const int* sc   = (const int*)d_in[4];
    float* out = (float*)d_out;

    half_t* Ah = (half_t*)d_ws;                                      // 12.58 MB
    half_t* Wh = (half_t*)((char*)d_ws + (size_t)M_DIM * K_DIM * 2); // 9.44 MB

    prep_all<<<PREP_BLOCKS, 256, 0, stream>>>(
        xr, xi, Cr, Ci, sc, Ah, Wh, out);

    dim3 grid(N2_DIM / BN, M_DIM / BM);   // (24, 32) = 768 blocks
    gemm_scatter<<<grid, 256, 0, stream>>>(Ah, Wh, sc, out);
}

// Round 5
// 151.679 us; speedup vs baseline: 1.0302x; 1.0090x over previous
//
#include <hip/hip_runtime.h>
#include <cstdint>
#include <cstddef>

// ---------------------------------------------------------------------------
// DeMash = complex GEMM: out[bts, m] = sum_l y[bts, l] * conj(C)[m, l]
//   out_r = Yr@Cr^T + Yi@Ci^T ; out_i = Yi@Cr^T - Yr@Ci^T
//
// R12: counted-vmcnt pipeline (T4, m218) on R11's geometry. R8-R11
// post-mortems: every schedule ending an iteration in an implicit
// vmcnt(0) drain (__syncthreads) lands at 47-68 us -- the drain IS the
// bottleneck. This loop never drains in steady state:
//   B1 (raw s_barrier)  : prev readers of buf[nb^1] are done
//   stage buf[nb^1]     : 4 gl2lds/thread, left IN FLIGHT
//   s_waitcnt vmcnt(4)  : only the 4 OLDEST loads (buf[nb], issued one
//                         full iteration ago) must have landed
//   B2 (raw s_barrier)  : all waves' buf[nb] complete
//   sched_barrier(0); ds_read buf[nb]; 16 MFMAs
// Geometry unchanged from R11 (proven occupancy point): 256 thr,
// 4 waves 2x2, 64x64 tile, BK=32 double-buffer, 32 KB LDS,
// 768 blocks = 3/CU, 12 waves/CU. prep_all unchanged (R9).
//   A2 [2048][3072] fp16 : [Yr(1536, zero-padded from 1512) | Yi(1536)]
//   W2 [1536][3072] fp16 : [Cr(1536) | Ci(1536)]
// Per-buffer row = 64 halves = 8 chunks of 16B; stage chunk g at slot
// g^(row&7), read chunk q at slot q^(fr&7); worst 2-way aliasing (free).
// ---------------------------------------------------------------------------

typedef _Float16 half_t;
typedef half_t half8 __attribute__((ext_vector_type(8)));
typedef half_t half4 __attribute__((ext_vector_type(4)));
typedef half_t half2_t __attribute__((ext_vector_type(2)));
typedef float floatx4 __attribute__((ext_vector_type(4)));
typedef float floatv4 __attribute__((ext_vector_type(4)));

#define M_DIM 2048
#define K_DIM 3072            // [Yr 1536 | Yi 1536]
#define L_PAD 1536            // 1512 padded to 48*32
#define N2_DIM 1536           // W2 rows (n' padded)
#define LDIM 1512
#define NSC 108
#define SYMS 14
#define FFT 128
#define ROWLEN (SYMS * FFT)   // 1792

#define BM 64
#define BN 64                 // N' tile (complex columns)
#define BK 32                 // l-step per iteration (per buffer)
#define NITER (L_PAD / BK)    // 48

// prep grid partition (blocks of 256 threads)
#define PA2_BLOCKS 6048   // A: 2048 rows x 14 syms x 54 j-pairs / 256
#define PW2_BLOCKS 4608   // W2: 1536 rows x 768 k-quads / 256
#define PAP_BLOCKS 48     // A pad zero: 2048 x 48 halves / 8 / 256
#define PG_BLOCKS 4480    // guard zero: 2*2048*14*20 / 256
#define PREP_BLOCKS (PA2_BLOCKS + PW2_BLOCKS + PAP_BLOCKS + PG_BLOCKS)

typedef __attribute__((address_space(3))) uint32_t lds_u32_t;
typedef const __attribute__((address_space(1))) uint32_t glob_u32_t;

__device__ __forceinline__ void gl2lds16(const void* g, void* l) {
    __builtin_amdgcn_global_load_lds((glob_u32_t*)g, (lds_u32_t*)l, 16, 0, 0);
}

// ---------------------------------------------------------------------------
// prep_all (one dispatch, 4 regions, wave-uniform region branch):
//  [0, PA2): A-build. Yr at col sym*108+2jp, Yi at +1536.
//  [PA2, +PW2): W2-build. row n'<1536: cols [0,1536)=Cr[n'], [1536,3072)=Ci.
//            zero when n'>=1512 or l>=1512. float4 load, half4 store.
//  then A pad zeros (cols 1512..1535 and 3048..3071), then guard zeros.
// ---------------------------------------------------------------------------
__global__ __launch_bounds__(256) void prep_all(
    const float* __restrict__ xr, const float* __restrict__ xi,
    const float* __restrict__ Cr, const float* __restrict__ Ci,
    const int* __restrict__ sc,
    half_t* __restrict__ A, half_t* __restrict__ W, float* __restrict__ out)
{
    const int b = blockIdx.x;
    const int t = threadIdx.x;

    if (b < PA2_BLOCKS) {
        int idx = b * 256 + t;          // [0, 2048*14*54)
        int jp = idx % 54;
        int rest = idx / 54;
        int sym = rest % 14;
        int row = rest / 14;
        int s0 = sc[2 * jp];
        int s1 = sc[2 * jp + 1];
        const float* xrp = xr + (size_t)row * ROWLEN + sym * FFT;
        const float* xip = xi + (size_t)row * ROWLEN + sym * FFT;
        half2_t hr = { (half_t)xrp[s0], (half_t)xrp[s1] };
        half2_t hi = { (half_t)xip[s0], (half_t)xip[s1] };
        size_t dst = (size_t)row * K_DIM + sym * NSC + 2 * jp;
        *(half2_t*)(A + dst) = hr;
        *(half2_t*)(A + dst + L_PAD) = hi;
    } else if (b < PA2_BLOCKS + PW2_BLOCKS) {
        int idx = (b - PA2_BLOCKS) * 256 + t;   // [0, 1536*768)
        int kq = idx % 768;
        int n = idx / 768;
        int k0 = kq * 4;
        floatv4 f = {0.0f, 0.0f, 0.0f, 0.0f};
        if (n < LDIM) {
            if (k0 < L_PAD) {
                if (k0 < LDIM)
                    f = *(const floatv4*)(Cr + (size_t)n * LDIM + k0);
            } else {
                int l = k0 - L_PAD;
                if (l < LDIM)
                    f = *(const floatv4*)(Ci + (size_t)n * LDIM + l);
            }
        }
        half4 h = { (half_t)f.x, (half_t)f.y, (half_t)f.z, (half_t)f.w };
        *(half4*)(W + (size_t)n * K_DIM + k0) = h;
    } else if (b < PA2_BLOCKS + PW2_BLOCKS + PAP_BLOCKS) {
        int idx = (b - PA2_BLOCKS - PW2_BLOCKS) * 256 + t;  // [0, 12288)
        int c = idx % 6;
        int row = idx / 6;
        int col = (c < 3) ? (LDIM + c * 8) : (L_PAD + LDIM + (c - 3) * 8);
        half8 z = {};
        *(half8*)(A + (size_t)row * K_DIM + col) = z;
    } else {
        // zero guard columns [0,10) U [118,128) for all 4096 rows x 14 syms
        int idx = (b - PA2_BLOCKS - PW2_BLOCKS - PAP_BLOCKS) * 256 + t;
        int c20 = idx % 20;
        int rest = idx / 20;
        int sym = rest % 14;
        int rowri = rest / 14;                 // [0, 4096) covers both ri
        int col = (c20 < 10) ? c20 : (NSC + c20);
        out[(size_t)rowri * ROWLEN + sym * FFT + col] = 0.0f;
    }
}

// ---------------------------------------------------------------------------
// gemm_scatter: complex 64x64 tile, 4 waves (2x2), each 32M x 32N'
// (2x2 frags x 4 products RR,II,IR,RI). Counted-vmcnt double-buffer,
// BK=32, two raw barriers/iter, NO vmcnt(0) in steady state.
// LDS 4 x 8 KB = 32 KB -> grid 768 = 3 blocks/CU, 12 waves/CU.
// ---------------------------------------------------------------------------
__global__ __launch_bounds__(256, 3) void gemm_scatter(
    const half_t* __restrict__ A,   // [M_DIM][K_DIM]  [Yr|Yi]
    const half_t* __restrict__ W,   // [N2_DIM][K_DIM] [Cr|Ci]
    const int* __restrict__ sc,
    float* __restrict__ out)        // [2][2048][14][128]; guards pre-zeroed
{
    __shared__ __align__(16) half_t As[2][BM * 2 * BK];   // 2 x 8 KB
    __shared__ __align__(16) half_t Ws[2][BN * 2 * BK];   // 2 x 8 KB

    const int t = threadIdx.x;        // 0..255
    const int bn = blockIdx.x;
    const int bm = blockIdx.y;
    const int lane = t & 63;
    const int w = t >> 6;             // 0..3
    const int wm = (w >> 1) * 32;     // wave M offset in tile
    const int wn = (w & 1) * 32;      // wave N' offset in tile

    floatx4 aRR[2][2] = {}, aII[2][2] = {}, aIR[2][2] = {}, aRI[2][2] = {};

    // staging: per buffer 512 chunks (16B); chunk c: row = c>>3,
    // slot = c&7, global chunk g = slot ^ (row&7); g<4 -> Yr/Cr col g*8,
    // g>=4 -> Yi/Ci col 1536+(g-4)*8. LDS dest = base + c*16.
    const half_t* gA[2];
    const half_t* gW[2];
    int lOff[2];
#pragma unroll
    for (int r = 0; r < 2; ++r) {
        int c = r * 256 + t;
        int row = c >> 3, slot = c & 7;
        int g = slot ^ (row & 7);
        int gcol = (g < 4) ? g * 8 : (L_PAD + (g - 4) * 8);
        gA[r] = A + (size_t)(bm * BM + row) * K_DIM + gcol;
        gW[r] = W + (size_t)(bn * BN + row) * K_DIM + gcol;
        lOff[r] = c * 8;
    }

    const int fr = lane & 15;         // fragment row (M or N' within 16)
    const int cr = lane >> 4;         // k-quad index within the 32-k step
    const int sR = (cr ^ (fr & 7)) * 8;            // Yr/Cr chunk slot
    const int sI = ((4 + cr) ^ (fr & 7)) * 8;      // Yi/Ci chunk slot

    // prologue: stage kb=0 into buf 0 (4 loads/thread, left in flight)
#pragma unroll
    for (int r = 0; r < 2; ++r) {
        gl2lds16(gA[r], &As[0][lOff[r]]);
        gl2lds16(gW[r], &Ws[0][lOff[r]]);
        gA[r] += BK; gW[r] += BK;
    }

    for (int kb = 0; kb < NITER; ++kb) {
        const int nb = kb & 1;

        // B1: all waves' prior-iter ds_reads of buf[nb^1] are done
        // (reads complete before MFMA consumption, which precedes B1).
        __builtin_amdgcn_s_barrier();

        if (kb < NITER - 1) {
            // stage next K-step into buf[nb^1]; loads stay in flight
#pragma unroll
            for (int r = 0; r < 2; ++r) {
                gl2lds16(gA[r], &As[nb ^ 1][lOff[r]]);
                gl2lds16(gW[r], &Ws[nb ^ 1][lOff[r]]);
                gA[r] += BK; gW[r] += BK;
            }
            // wait only the 4 OLDEST loads (buf[nb], issued last iter)
            asm volatile("s_waitcnt vmcnt(4)" ::: "memory");
        } else {
            asm volatile("s_waitcnt vmcnt(0)" ::: "memory");
        }

        // B2: every wave's buf[nb] contribution has landed
        __builtin_amdgcn_s_barrier();
        __builtin_amdgcn_sched_barrier(0);

        half8 yr[2], yi[2], cRf[2], cIf[2];
#pragma unroll
        for (int i = 0; i < 2; ++i) {
            const half_t* rb = &As[nb][(wm + i * 16 + fr) * (2 * BK)];
            yr[i] = *(const half8*)(rb + sR);
            yi[i] = *(const half8*)(rb + sI);
        }
#pragma unroll
        for (int j = 0; j < 2; ++j) {
            const half_t* rb = &Ws[nb][(wn + j * 16 + fr) * (2 * BK)];
            cRf[j] = *(const half8*)(rb + sR);
            cIf[j] = *(const half8*)(rb + sI);
        }
#pragma unroll
        for (int i = 0; i < 2; ++i)
#pragma unroll
            for (int j = 0; j < 2; ++j) {
                aRR[i][j] = __builtin_amdgcn_mfma_f32_16x16x32_f16(
                    yr[i], cRf[j], aRR[i][j], 0, 0, 0);
                aII[i][j] = __builtin_amdgcn_mfma_f32_16x16x32_f16(
                    yi[i], cIf[j], aII[i][j], 0, 0, 0);
                aIR[i][j] = __builtin_amdgcn_mfma_f32_16x16x32_f16(
                    yi[i], cRf[j], aIR[i][j], 0, 0, 0);
                aRI[i][j] = __builtin_amdgcn_mfma_f32_16x16x32_f16(
                    yr[i], cIf[j], aRI[i][j], 0, 0, 0);
            }
    }

    // epilogue: C/D layout col = lane&15 (N'), row = (lane>>4)*4 + reg (M)
    const int rq = lane >> 4;
#pragma unroll
    for (int j = 0; j < 2; ++j) {
        int n = bn * BN + wn + j * 16 + fr;
        if (n >= LDIM) continue;               // N'-pad: discard
        int sym = n / NSC;
        int jj = n - sym * NSC;
        size_t colR = (size_t)sym * FFT + sc[jj];
        size_t colI = (size_t)M_DIM * ROWLEN + colR;
#pragma unroll
        for (int i = 0; i < 2; ++i) {
            int m0 = bm * BM + wm + i * 16 + rq * 4;
#pragma unroll
            for (int r = 0; r < 4; ++r) {
                float vr = aRR[i][j][r] + aII[i][j][r];
                float vi = aIR[i][j][r] - aRI[i][j][r];
                out[colR + (size_t)(m0 + r) * ROWLEN] = vr;
                out[colI + (size_t)(m0 + r) * ROWLEN] = vi;
            }
        }
    }
}

// ---------------------------------------------------------------------------
extern "C" void kernel_launch(void* const* d_in, const int* in_sizes, int n_in,
                              void* d_out, int out_size, void* d_ws, size_t ws_size,
                              hipStream_t stream) {
    const float* xr = (const float*)d_in[0];
    const float* xi = (const float*)d_in[1];
    const float* Cr = (const float*)d_in[2];
    const float* Ci = (const float*)d_in[3];
    const int* sc   = (const int*)d_in[4];
    float* out = (float*)d_out;

    half_t* Ah = (half_t*)d_ws;                                      // 12.58 MB
    half_t* Wh = (half_t*)((char*)d_ws + (size_t)M_DIM * K_DIM * 2); // 9.44 MB

    prep_all<<<PREP_BLOCKS, 256, 0, stream>>>(
        xr, xi, Cr, Ci, sc, Ah, Wh, out);

    dim3 grid(N2_DIM / BN, M_DIM / BM);   // (24, 32) = 768 blocks
    gemm_scatter<<<grid, 256, 0, stream>>>(Ah, Wh, sc, out);
}

// Round 6
// 146.970 us; speedup vs baseline: 1.0632x; 1.0320x over previous
//
#include <hip/hip_runtime.h>
#include <cstdint>
#include <cstddef>

// ---------------------------------------------------------------------------
// DeMash = complex GEMM: out[bts, m] = sum_l y[bts, l] * conj(C)[m, l]
//   out_r = Yr@Cr^T + Yi@Ci^T ; out_i = Yi@Cr^T - Yr@Ci^T
//
// R13: R9 skeleton (proven best: 2-barrier single-buffer, 4 waves 2x2,
// 64x64 tile, 3 blocks/CU, 12 waves/CU) + two orthogonal low-risk levers:
//  (1) BK 64->96: NITER 24->16. R11 measured ~670 ns/iter of fixed
//      per-iteration cost (24->48 iters = +16 us at constant bytes);
//      -8 iters predicts -4..5 us. LDS 2x24 KB = 48 KB -> 3 blocks/CU.
//  (2) XCD-chunked blockIdx swizzle (T1): 768 = 8 x 96; each XCD gets
//      96 consecutive tiles = 4 full bm-rows -> A-panels XCD-L2-resident,
//      W re-reads temporally local. Shortens the L2/L3-latency-bound
//      staging drains.
// All schedule experiments (R10-R12 dbuf/counted-vmcnt) regressed; the
// load phase per iter exceeds the compute phase at this tile size, so
// 1-deep pipelines cannot hide it. Fatter iters + better locality instead.
//   A2 [2048][3072] fp16 : [Yr(1536, zero-padded from 1512) | Yi(1536)]
//   W2 [1536][3072] fp16 : [Cr(1536) | Ci(1536)]
// Row in LDS = 192 halves = 24 chunks of 16B, swizzled within each
// 8-chunk (128 B) group: slot = (q&~7) | ((q&7)^(row&7)) -- same 2-way
// worst-case bank aliasing as R9 (free, m136). prep_all unchanged.
// ---------------------------------------------------------------------------

typedef _Float16 half_t;
typedef half_t half8 __attribute__((ext_vector_type(8)));
typedef half_t half4 __attribute__((ext_vector_type(4)));
typedef half_t half2_t __attribute__((ext_vector_type(2)));
typedef float floatx4 __attribute__((ext_vector_type(4)));
typedef float floatv4 __attribute__((ext_vector_type(4)));

#define M_DIM 2048
#define K_DIM 3072            // [Yr 1536 | Yi 1536]
#define L_PAD 1536            // 1512 padded to 16*96
#define N2_DIM 1536           // W2 rows (n' padded)
#define LDIM 1512
#define NSC 108
#define SYMS 14
#define FFT 128
#define ROWLEN (SYMS * FFT)   // 1792

#define BM 64
#define BN 64                 // N' tile (complex columns)
#define BK 96                 // l-step per iteration
#define NITER (L_PAD / BK)    // 16
#define ROWH (2 * BK)         // 192 halves per LDS row
#define CPR 24                // 16B chunks per LDS row

// prep grid partition (blocks of 256 threads)
#define PA2_BLOCKS 6048   // A: 2048 rows x 14 syms x 54 j-pairs / 256
#define PW2_BLOCKS 4608   // W2: 1536 rows x 768 k-quads / 256
#define PAP_BLOCKS 48     // A pad zero: 2048 x 48 halves / 8 / 256
#define PG_BLOCKS 4480    // guard zero: 2*2048*14*20 / 256
#define PREP_BLOCKS (PA2_BLOCKS + PW2_BLOCKS + PAP_BLOCKS + PG_BLOCKS)

typedef __attribute__((address_space(3))) uint32_t lds_u32_t;
typedef const __attribute__((address_space(1))) uint32_t glob_u32_t;

__device__ __forceinline__ void gl2lds16(const void* g, void* l) {
    __builtin_amdgcn_global_load_lds((glob_u32_t*)g, (lds_u32_t*)l, 16, 0, 0);
}

// ---------------------------------------------------------------------------
// prep_all (one dispatch, 4 regions, wave-uniform region branch):
//  [0, PA2): A-build. Yr at col sym*108+2jp, Yi at +1536.
//  [PA2, +PW2): W2-build. row n'<1536: cols [0,1536)=Cr[n'], [1536,3072)=Ci.
//            zero when n'>=1512 or l>=1512. float4 load, half4 store.
//  then A pad zeros (cols 1512..1535 and 3048..3071), then guard zeros.
// ---------------------------------------------------------------------------
__global__ __launch_bounds__(256) void prep_all(
    const float* __restrict__ xr, const float* __restrict__ xi,
    const float* __restrict__ Cr, const float* __restrict__ Ci,
    const int* __restrict__ sc,
    half_t* __restrict__ A, half_t* __restrict__ W, float* __restrict__ out)
{
    const int b = blockIdx.x;
    const int t = threadIdx.x;

    if (b < PA2_BLOCKS) {
        int idx = b * 256 + t;          // [0, 2048*14*54)
        int jp = idx % 54;
        int rest = idx / 54;
        int sym = rest % 14;
        int row = rest / 14;
        int s0 = sc[2 * jp];
        int s1 = sc[2 * jp + 1];
        const float* xrp = xr + (size_t)row * ROWLEN + sym * FFT;
        const float* xip = xi + (size_t)row * ROWLEN + sym * FFT;
        half2_t hr = { (half_t)xrp[s0], (half_t)xrp[s1] };
        half2_t hi = { (half_t)xip[s0], (half_t)xip[s1] };
        size_t dst = (size_t)row * K_DIM + sym * NSC + 2 * jp;
        *(half2_t*)(A + dst) = hr;
        *(half2_t*)(A + dst + L_PAD) = hi;
    } else if (b < PA2_BLOCKS + PW2_BLOCKS) {
        int idx = (b - PA2_BLOCKS) * 256 + t;   // [0, 1536*768)
        int kq = idx % 768;
        int n = idx / 768;
        int k0 = kq * 4;
        floatv4 f = {0.0f, 0.0f, 0.0f, 0.0f};
        if (n < LDIM) {
            if (k0 < L_PAD) {
                if (k0 < LDIM)
                    f = *(const floatv4*)(Cr + (size_t)n * LDIM + k0);
            } else {
                int l = k0 - L_PAD;
                if (l < LDIM)
                    f = *(const floatv4*)(Ci + (size_t)n * LDIM + l);
            }
        }
        half4 h = { (half_t)f.x, (half_t)f.y, (half_t)f.z, (half_t)f.w };
        *(half4*)(W + (size_t)n * K_DIM + k0) = h;
    } else if (b < PA2_BLOCKS + PW2_BLOCKS + PAP_BLOCKS) {
        int idx = (b - PA2_BLOCKS - PW2_BLOCKS) * 256 + t;  // [0, 12288)
        int c = idx % 6;
        int row = idx / 6;
        int col = (c < 3) ? (LDIM + c * 8) : (L_PAD + LDIM + (c - 3) * 8);
        half8 z = {};
        *(half8*)(A + (size_t)row * K_DIM + col) = z;
    } else {
        // zero guard columns [0,10) U [118,128) for all 4096 rows x 14 syms
        int idx = (b - PA2_BLOCKS - PW2_BLOCKS - PAP_BLOCKS) * 256 + t;
        int c20 = idx % 20;
        int rest = idx / 20;
        int sym = rest % 14;
        int rowri = rest / 14;                 // [0, 4096) covers both ri
        int col = (c20 < 10) ? c20 : (NSC + c20);
        out[(size_t)rowri * ROWLEN + sym * FFT + col] = 0.0f;
    }
}

// ---------------------------------------------------------------------------
// gemm_scatter: complex 64x64 tile, 4 waves (2x2), each 32M x 32N'
// (2x2 frags x 4 products RR,II,IR,RI). R9 2-barrier single-buffer
// schedule, BK=96 (16 iters). LDS 24+24 = 48 KB -> 3 blocks/CU,
// 12 waves/CU. XCD-chunked block swizzle (768 = 8 x 96).
// Row = 24 chunks; stage chunk g at slot (g&~7)|((g&7)^(row&7));
// read chunk q from slot (q&~7)|((q&7)^(fr&7)).
// ---------------------------------------------------------------------------
__global__ __launch_bounds__(256, 3) void gemm_scatter(
    const half_t* __restrict__ A,   // [M_DIM][K_DIM]  [Yr|Yi]
    const half_t* __restrict__ W,   // [N2_DIM][K_DIM] [Cr|Ci]
    const int* __restrict__ sc,
    float* __restrict__ out)        // [2][2048][14][128]; guards pre-zeroed
{
    __shared__ __align__(16) half_t As[BM * ROWH];   // 24 KB
    __shared__ __align__(16) half_t Ws[BN * ROWH];   // 24 KB

    const int t = threadIdx.x;        // 0..255
    // XCD-chunked swizzle: 768 blocks = 8 XCDs x 96; each XCD owns 96
    // consecutive tiles = 4 full bm-rows (A-panels L2-resident per XCD).
    const int bid = blockIdx.x;
    const int nbid = (bid & 7) * 96 + (bid >> 3);
    const int bn = nbid % 24;
    const int bm = nbid / 24;
    const int lane = t & 63;
    const int w = t >> 6;             // 0..3
    const int wm = (w >> 1) * 32;     // wave M offset in tile
    const int wn = (w & 1) * 32;      // wave N' offset in tile

    floatx4 aRR[2][2] = {}, aII[2][2] = {}, aIR[2][2] = {}, aRI[2][2] = {};

    // staging: 1536 chunks (16B) per matrix per iter; chunk c:
    // row = c/24, slot = c%24, global chunk g = (slot&~7)|((slot&7)^(row&7));
    // g<12 -> Yr/Cr col g*8, g>=12 -> Yi/Ci col 1536+(g-12)*8.
    // LDS dest = c*16 (contiguous per lane).
    const half_t* gA[6];
    const half_t* gW[6];
    int lOff[6];
#pragma unroll
    for (int r = 0; r < 6; ++r) {
        int c = r * 256 + t;
        int row = c / CPR, slot = c % CPR;
        int g = (slot & ~7) | ((slot & 7) ^ (row & 7));
        int gcol = (g < 12) ? g * 8 : (L_PAD + (g - 12) * 8);
        gA[r] = A + (size_t)(bm * BM + row) * K_DIM + gcol;
        gW[r] = W + (size_t)(bn * BN + row) * K_DIM + gcol;
        lOff[r] = c * 8;
    }

    const int fr = lane & 15;         // fragment row (M or N' within 16)
    const int cr = lane >> 4;         // k-quad index within a 32-k step
    const int frl = fr & 7;

    for (int kb = 0; kb < NITER; ++kb) {
        __syncthreads();
#pragma unroll
        for (int r = 0; r < 6; ++r) {
            gl2lds16(gA[r], &As[lOff[r]]);
            gl2lds16(gW[r], &Ws[lOff[r]]);
        }
#pragma unroll
        for (int r = 0; r < 6; ++r) { gA[r] += BK; gW[r] += BK; }
        __syncthreads();

#pragma unroll
        for (int ss = 0; ss < 3; ++ss) {
            // Yr/Cr chunk q = ss*4+cr in [0,12); Yi/Ci chunk 12+ss*4+cr.
            const int qR = ss * 4 + cr;
            const int qI = 12 + ss * 4 + cr;
            const int sR = ((qR & ~7) | ((qR & 7) ^ frl)) * 8;
            const int sI = ((qI & ~7) | ((qI & 7) ^ frl)) * 8;
            half8 yr[2], yi[2], cRf[2], cIf[2];
#pragma unroll
            for (int i = 0; i < 2; ++i) {
                const half_t* rb = &As[(wm + i * 16 + fr) * ROWH];
                yr[i] = *(const half8*)(rb + sR);
                yi[i] = *(const half8*)(rb + sI);
            }
#pragma unroll
            for (int j = 0; j < 2; ++j) {
                const half_t* rb = &Ws[(wn + j * 16 + fr) * ROWH];
                cRf[j] = *(const half8*)(rb + sR);
                cIf[j] = *(const half8*)(rb + sI);
            }
#pragma unroll
            for (int i = 0; i < 2; ++i)
#pragma unroll
                for (int j = 0; j < 2; ++j) {
                    aRR[i][j] = __builtin_amdgcn_mfma_f32_16x16x32_f16(
                        yr[i], cRf[j], aRR[i][j], 0, 0, 0);
                    aII[i][j] = __builtin_amdgcn_mfma_f32_16x16x32_f16(
                        yi[i], cIf[j], aII[i][j], 0, 0, 0);
                    aIR[i][j] = __builtin_amdgcn_mfma_f32_16x16x32_f16(
                        yi[i], cRf[j], aIR[i][j], 0, 0, 0);
                    aRI[i][j] = __builtin_amdgcn_mfma_f32_16x16x32_f16(
                        yr[i], cIf[j], aRI[i][j], 0, 0, 0);
                }
        }
    }

    // epilogue: C/D layout col = lane&15 (N'), row = (lane>>4)*4 + reg (M)
    const int rq = lane >> 4;
#pragma unroll
    for (int j = 0; j < 2; ++j) {
        int n = bn * BN + wn + j * 16 + fr;
        if (n >= LDIM) continue;               // N'-pad: discard
        int sym = n / NSC;
        int jj = n - sym * NSC;
        size_t colR = (size_t)sym * FFT + sc[jj];
        size_t colI = (size_t)M_DIM * ROWLEN + colR;
#pragma unroll
        for (int i = 0; i < 2; ++i) {
            int m0 = bm * BM + wm + i * 16 + rq * 4;
#pragma unroll
            for (int r = 0; r < 4; ++r) {
                float vr = aRR[i][j][r] + aII[i][j][r];
                float vi = aIR[i][j][r] - aRI[i][j][r];
                out[colR + (size_t)(m0 + r) * ROWLEN] = vr;
                out[colI + (size_t)(m0 + r) * ROWLEN] = vi;
            }
        }
    }
}

// ---------------------------------------------------------------------------
extern "C" void kernel_launch(void* const* d_in, const int* in_sizes, int n_in,
                              void* d_out, int out_size, void* d_ws, size_t ws_size,
                              hipStream_t stream) {
    const float* xr = (const float*)d_in[0];
    const float* xi = (const float*)d_in[1];
    const float* Cr = (const float*)d_in[2];
    const float* Ci = (const float*)d_in[3];
    const int* sc   = (const int*)d_in[4];
    float* out = (float*)d_out;

    half_t* Ah = (half_t*)d_ws;                                      // 12.58 MB
    half_t* Wh = (half_t*)((char*)d_ws + (size_t)M_DIM * K_DIM * 2); // 9.44 MB

    prep_all<<<PREP_BLOCKS, 256, 0, stream>>>(
        xr, xi, Cr, Ci, sc, Ah, Wh, out);

    gemm_scatter<<<768, 256, 0, stream>>>(Ah, Wh, sc, out);
}